// Round 8
// baseline (345.836 us; speedup 1.0000x reference)
//
#include <hip/hip_runtime.h>
#include <math.h>

#define TDIM   1032
#define DIM    1024
#define SLEN   2048
#define BATCH  2
#define NROWS  (SLEN*BATCH)   // 4096
#define NHEAD  16
#define HD     64

typedef unsigned short u16;
typedef short short8 __attribute__((ext_vector_type(8)));
typedef short bf16x4 __attribute__((ext_vector_type(4)));
typedef float f32x4  __attribute__((ext_vector_type(4)));

#define CSCALE 0.18033688011112042f   // 0.125 * log2(e), folded into Q

__device__ inline unsigned fbits(float x) {
    union { float f; unsigned u; } v; v.f = x; return v.u;
}
__device__ inline float asfloat(unsigned u) {
    union { unsigned u; float f; } v; v.u = u; return v.f;
}
__device__ inline u16 f2bf_rne(float x) {
    unsigned u = fbits(x);
    unsigned r = u + 0x7fffu + ((u >> 16) & 1u);
    return (u16)(r >> 16);
}
__device__ inline float bf2f(u16 b) { return asfloat(((unsigned)b) << 16); }
__device__ inline void dma16(const u16* g, u16* l) {
    __builtin_amdgcn_global_load_lds(
        (const __attribute__((address_space(1))) void*)g,
        (__attribute__((address_space(3))) void*)l, 16, 0, 0);
}

// ---------------------------------------------------------------------------
// Kernel 1: conv 9x9 over template -> Wh/Wl bf16 hi/lo split directly.
// ---------------------------------------------------------------------------
__global__ __launch_bounds__(256) void conv_weight_kernel(
    const float* __restrict__ tmpl,
    const float* __restrict__ cw0, const float* __restrict__ cb0,
    const float* __restrict__ cw1, const float* __restrict__ cb1,
    const float* __restrict__ cw2, const float* __restrict__ cb2,
    u16* __restrict__ Wh, u16* __restrict__ Wl)
{
    int t = blockIdx.z;
    const float* cw = (t == 0) ? cw0 : ((t == 1) ? cw1 : cw2);
    const float* cb = (t == 0) ? cb0 : ((t == 1) ? cb1 : cb2);
    __shared__ float scw[81];
    if (threadIdx.x < 81) scw[threadIdx.x] = cw[threadIdx.x];
    __syncthreads();
    int i = blockIdx.x * 256 + threadIdx.x;
    int o = blockIdx.y;
    float acc = cb[0];
    #pragma unroll
    for (int dy = 0; dy < 9; ++dy) {
        const float* trow = tmpl + (size_t)(o + dy) * TDIM + i;
        #pragma unroll
        for (int dx = 0; dx < 9; ++dx)
            acc = fmaf(scw[dy * 9 + dx], trow[dx], acc);
    }
    size_t idx = (size_t)t * DIM * DIM + (size_t)o * DIM + i;
    u16 h = f2bf_rne(acc);
    Wh[idx] = h;
    Wl[idx] = f2bf_rne(acc - bf2f(h));
}

// ---------------------------------------------------------------------------
// Kernel 2: MFMA GEMM v2 — single-barrier double-buffered K-loop.
// Y[t] = X[t] @ W[t]^T + b[t]. Q,K: 3-term bf16 hi/lo; V: single-term bf16
// (error budget analysis: adds <=0.08 abs to output, threshold 1.62).
// Iter: issue B-DMA(it+1->buf^1) + convert/write A(it+1->buf^1) + prefetch
// xa(it+2); frag-read buf[cur]; MFMA; ONE barrier.
// ---------------------------------------------------------------------------
__global__ __launch_bounds__(256, 2) void qkv_mfma_gemm(
    const float* __restrict__ x0, const float* __restrict__ x1,
    const float* __restrict__ x2,
    const u16* __restrict__ Whg, const u16* __restrict__ Wlg,
    const float* __restrict__ b0, const float* __restrict__ b1,
    const float* __restrict__ b2,
    u16* __restrict__ Qh, u16* __restrict__ Ql,
    u16* __restrict__ Kh, u16* __restrict__ Kl,
    u16* __restrict__ Vb)
{
    int t = blockIdx.z;
    const float* X    = (t == 0) ? x0 : ((t == 1) ? x1 : x2);
    const u16* Bh_g   = Whg + (size_t)t * DIM * DIM;
    const u16* Bl_g   = Wlg + (size_t)t * DIM * DIM;
    const float* bias = (t == 0) ? b0 : ((t == 1) ? b1 : b2);

    // [buf][tile: Ah,Al,Bh,Bl][128 rows x 32 u16] = 64 KB
    __shared__ __align__(16) u16 sAh[2][4096], sAl[2][4096];
    __shared__ __align__(16) u16 sBh[2][4096], sBl[2][4096];

    int tid = threadIdx.x;
    int w = tid >> 6, lane = tid & 63;
    int c = lane & 15, quad = lane >> 4;
    int m0 = blockIdx.y * 128, n0 = blockIdx.x * 128;
    int mh = (w >> 1) * 64, nh = (w & 1) * 64;

    int arow = w * 32 + (lane & 31);
    int acol = (lane >> 5) * 16;
    const float* aptr = X + (size_t)(m0 + arow) * DIM + acol;

    int srow = lane >> 2, sgr = lane & 3;

    f32x4 acc[4][4];
    #pragma unroll
    for (int i = 0; i < 4; ++i)
        #pragma unroll
        for (int j = 0; j < 4; ++j)
            #pragma unroll
            for (int r = 0; r < 4; ++r) acc[i][j][r] = 0.0f;

    float bias_v[4];
    #pragma unroll
    for (int tn = 0; tn < 4; ++tn) bias_v[tn] = bias[n0 + nh + tn * 16 + c];

    #define ISSUE_BDMA(itv, bufv) do {                                         \
        int kg_ = (itv) * 4;                                                   \
        _Pragma("unroll")                                                      \
        for (int i_ = 0; i_ < 2; ++i_) {                                       \
            int rb_ = w * 32 + i_ * 16;                                        \
            const u16* gh_ = Bh_g + (size_t)(n0 + rb_ + srow) * DIM + (kg_ + sgr) * 8; \
            dma16(gh_, sBh[bufv] + rb_ * 32);                                  \
            if (t < 2) {                                                       \
                const u16* gl_ = Bl_g + (size_t)(n0 + rb_ + srow) * DIM + (kg_ + sgr) * 8; \
                dma16(gl_, sBl[bufv] + rb_ * 32);                              \
            }                                                                  \
        }                                                                      \
    } while (0)

    #define WRITE_A(bufv) do {                                                 \
        _Pragma("unroll")                                                      \
        for (int g_ = 0; g_ < 2; ++g_) {                                       \
            float v_[8] = { xa[2*g_].x, xa[2*g_].y, xa[2*g_].z, xa[2*g_].w,    \
                            xa[2*g_+1].x, xa[2*g_+1].y, xa[2*g_+1].z, xa[2*g_+1].w }; \
            short8 hv_, lv_;                                                   \
            _Pragma("unroll")                                                  \
            for (int e_ = 0; e_ < 8; ++e_) {                                   \
                unsigned u_ = fbits(v_[e_]);                                   \
                hv_[e_] = (short)(u_ >> 16);                                   \
                if (t < 2) {                                                   \
                    float l_ = v_[e_] - asfloat(u_ & 0xffff0000u);             \
                    lv_[e_] = (short)(fbits(l_) >> 16);                        \
                }                                                              \
            }                                                                  \
            *(short8*)(sAh[bufv] + arow * 32 + acol + g_ * 8) = hv_;           \
            if (t < 2)                                                         \
                *(short8*)(sAl[bufv] + arow * 32 + acol + g_ * 8) = lv_;       \
        }                                                                      \
    } while (0)

    float4 xa[4];
    // ---- prologue: fill buf0 for it=0 ----
    ISSUE_BDMA(0, 0);
    #pragma unroll
    for (int j = 0; j < 4; ++j) xa[j] = *(const float4*)(aptr + j * 4);
    WRITE_A(0);
    #pragma unroll
    for (int j = 0; j < 4; ++j) xa[j] = *(const float4*)(aptr + 32 + j * 4);
    __syncthreads();   // DMA(0) + A(0) writes drained

    for (int it = 0; it < 32; ++it) {
        int cur = it & 1;
        // ---- stage it+1 into buf^1 (free since last barrier) ----
        if (it < 31) {
            ISSUE_BDMA(it + 1, cur ^ 1);
            WRITE_A(cur ^ 1);
            if (it < 30) {
                #pragma unroll
                for (int j = 0; j < 4; ++j)
                    xa[j] = *(const float4*)(aptr + (it + 2) * 32 + j * 4);
            }
        }

        // ---- fragments from buf[cur] ----
        short8 ah[4], bh[4];
        #pragma unroll
        for (int tt = 0; tt < 4; ++tt) {
            ah[tt] = *(short8*)(sAh[cur] + (mh + tt * 16 + c) * 32 + quad * 8);
            bh[tt] = *(short8*)(sBh[cur] + (nh + tt * 16 + c) * 32 + quad * 8);
        }
        if (t < 2) {
            short8 al[4], bl[4];
            #pragma unroll
            for (int tt = 0; tt < 4; ++tt) {
                al[tt] = *(short8*)(sAl[cur] + (mh + tt * 16 + c) * 32 + quad * 8);
                bl[tt] = *(short8*)(sBl[cur] + (nh + tt * 16 + c) * 32 + quad * 8);
            }
            #pragma unroll
            for (int tm = 0; tm < 4; ++tm)
                #pragma unroll
                for (int tn = 0; tn < 4; ++tn) {
                    acc[tm][tn] = __builtin_amdgcn_mfma_f32_16x16x32_bf16(
                        ah[tm], bh[tn], acc[tm][tn], 0, 0, 0);
                    acc[tm][tn] = __builtin_amdgcn_mfma_f32_16x16x32_bf16(
                        ah[tm], bl[tn], acc[tm][tn], 0, 0, 0);
                    acc[tm][tn] = __builtin_amdgcn_mfma_f32_16x16x32_bf16(
                        al[tm], bh[tn], acc[tm][tn], 0, 0, 0);
                }
        } else {
            #pragma unroll
            for (int tm = 0; tm < 4; ++tm)
                #pragma unroll
                for (int tn = 0; tn < 4; ++tn)
                    acc[tm][tn] = __builtin_amdgcn_mfma_f32_16x16x32_bf16(
                        ah[tm], bh[tn], acc[tm][tn], 0, 0, 0);
        }
        __syncthreads();   // readers of buf[cur] done; buf[cur] free for it+2
    }
    #undef ISSUE_BDMA
    #undef WRITE_A

    // ---- epilogue: trunc-hi/lo split; Q pre-scaled by CSCALE ----
    if (t < 2) {
        u16* Yh = (t == 0) ? Qh : Kh;
        u16* Yl = (t == 0) ? Ql : Kl;
        float qs = (t == 0) ? CSCALE : 1.0f;
        #pragma unroll
        for (int tm = 0; tm < 4; ++tm)
            #pragma unroll
            for (int r = 0; r < 4; ++r) {
                int m = m0 + mh + tm * 16 + quad * 4 + r;
                #pragma unroll
                for (int tn = 0; tn < 4; ++tn) {
                    int n = n0 + nh + tn * 16 + c;
                    float o = (acc[tm][tn][r] + bias_v[tn]) * qs;
                    unsigned bo = fbits(o);
                    Yh[(size_t)m * DIM + n] = (u16)(bo >> 16);
                    float l = o - asfloat(bo & 0xffff0000u);
                    Yl[(size_t)m * DIM + n] = (u16)(fbits(l) >> 16);
                }
            }
    } else {
        #pragma unroll
        for (int tm = 0; tm < 4; ++tm)
            #pragma unroll
            for (int r = 0; r < 4; ++r) {
                int m = m0 + mh + tm * 16 + quad * 4 + r;
                #pragma unroll
                for (int tn = 0; tn < 4; ++tn) {
                    int n = n0 + nh + tn * 16 + c;
                    Vb[(size_t)m * DIM + n] =
                        (u16)(fbits(acc[tm][tn][r] + bias_v[tn]) >> 16);
                }
            }
    }
}

// ---------------------------------------------------------------------------
// Kernel 3: V bf16 [s*B+b][h*64+d] -> Vt bf16 [b][h][d][s]
// ---------------------------------------------------------------------------
__global__ __launch_bounds__(256) void vt_kernel(
    const u16* __restrict__ Vb, u16* __restrict__ Vt)
{
    int b = blockIdx.z, h = blockIdx.y, s0 = blockIdx.x * 64;
    __shared__ __align__(16) u16 tile[64][80];
    int tid = threadIdx.x;
    int sl = tid >> 2, d0 = (tid & 3) * 16;
    const u16* src = Vb + (size_t)((s0 + sl) * BATCH + b) * DIM + h * HD + d0;
    short8 v0 = *(const short8*)src;
    short8 v1 = *(const short8*)(src + 8);
    #pragma unroll
    for (int j = 0; j < 8; ++j) {
        tile[d0 + j][sl] = (u16)v0[j];
        tile[d0 + 8 + j][sl] = (u16)v1[j];
    }
    __syncthreads();
    int d = tid >> 2, sc0 = (tid & 3) * 16;
    u16* dst = Vt + (size_t)((b * NHEAD + h) * HD + d) * SLEN + s0 + sc0;
    *(short8*)dst = *(const short8*)&tile[d][sc0];
    *(short8*)(dst + 8) = *(const short8*)&tile[d][sc0 + 8];
}

// ---------------------------------------------------------------------------
// Kernel 4: MFMA flash attention (R7 verified — unchanged).
// ---------------------------------------------------------------------------
__global__ __launch_bounds__(256) void attn_mfma_kernel(
    const u16* __restrict__ Qh, const u16* __restrict__ Ql,
    const u16* __restrict__ Kh, const u16* __restrict__ Kl,
    const u16* __restrict__ Vt, float* __restrict__ out)
{
    int b = blockIdx.z, h = blockIdx.y;
    int q0 = blockIdx.x * 128;
    int tid = threadIdx.x;
    int w = tid >> 6, lane = tid & 63;
    int c = lane & 15, quad = lane >> 4;

    __shared__ __align__(16) u16 sbuf[2][3][4096];
    __shared__ __align__(16) u16 sP[4][2048];

    short8 qhf[2][2], qlf[2][2];
    #pragma unroll
    for (int u = 0; u < 2; ++u) {
        int s = q0 + w * 32 + u * 16 + c;
        size_t base = (size_t)(s * BATCH + b) * DIM + h * HD + quad * 8;
        qhf[u][0] = *(const short8*)(Qh + base);
        qhf[u][1] = *(const short8*)(Qh + base + 32);
        qlf[u][0] = *(const short8*)(Ql + base);
        qlf[u][1] = *(const short8*)(Ql + base + 32);
    }

    f32x4 acc[2][4];
    #pragma unroll
    for (int u = 0; u < 2; ++u)
        #pragma unroll
        for (int i = 0; i < 4; ++i)
            #pragma unroll
            for (int r = 0; r < 4; ++r) acc[u][i][r] = 0.0f;
    float m_run[2] = {-1e38f, -1e38f}, l_run[2] = {0.0f, 0.0f};

    int r3 = lane >> 3, c3 = lane & 7;
    int sw = c3 ^ r3;
    const size_t bhofs = (size_t)(b * NHEAD + h) * HD;

    #define ISSUE_DMA(n0v, bufv) do {                                          \
        _Pragma("unroll")                                                      \
        for (int j = 0; j < 2; ++j) {                                          \
            int i_ = 2 * w + j;                                                \
            int row_ = i_ * 8 + r3;                                            \
            size_t gk = (size_t)(((n0v) + row_) * BATCH + b) * DIM + h * HD + sw * 8; \
            dma16(Kh + gk, &sbuf[bufv][0][i_ * 512]);                          \
            dma16(Kl + gk, &sbuf[bufv][1][i_ * 512]);                          \
            size_t gv = (bhofs + row_) * SLEN + (n0v) + sw * 8;                \
            dma16(Vt + gv, &sbuf[bufv][2][i_ * 512]);                          \
        }                                                                      \
    } while (0)

    ISSUE_DMA(0, 0);

    for (int it = 0; it < 32; ++it) {
        int cur = it & 1;
        __syncthreads();
        if (it < 31) ISSUE_DMA((it + 1) * 64, cur ^ 1);

        const u16* bKh = sbuf[cur][0];
        const u16* bKl = sbuf[cur][1];
        const u16* bVt = sbuf[cur][2];

        f32x4 sc[2][4];
        #pragma unroll
        for (int ct = 0; ct < 4; ++ct) {
            int row = ct * 16 + c, rw = row & 7;
            int kb = row * 64;
            short8 kh0 = *(const short8*)(bKh + kb + ((quad ^ rw) * 8));
            short8 kh1 = *(const short8*)(bKh + kb + (((4 + quad) ^ rw) * 8));
            short8 kl0 = *(const short8*)(bKl + kb + ((quad ^ rw) * 8));
            short8 kl1 = *(const short8*)(bKl + kb + (((4 + quad) ^ rw) * 8));
            #pragma unroll
            for (int u = 0; u < 2; ++u) {
                f32x4 s = {0.0f, 0.0f, 0.0f, 0.0f};
                s = __builtin_amdgcn_mfma_f32_16x16x32_bf16(kh0, qhf[u][0], s, 0, 0, 0);
                s = __builtin_amdgcn_mfma_f32_16x16x32_bf16(kh1, qhf[u][1], s, 0, 0, 0);
                s = __builtin_amdgcn_mfma_f32_16x16x32_bf16(kh0, qlf[u][0], s, 0, 0, 0);
                s = __builtin_amdgcn_mfma_f32_16x16x32_bf16(kh1, qlf[u][1], s, 0, 0, 0);
                s = __builtin_amdgcn_mfma_f32_16x16x32_bf16(kl0, qhf[u][0], s, 0, 0, 0);
                s = __builtin_amdgcn_mfma_f32_16x16x32_bf16(kl1, qhf[u][1], s, 0, 0, 0);
                sc[u][ct] = s;
            }
        }

        u16* wp = sP[w];
        #pragma unroll
        for (int u = 0; u < 2; ++u) {
            float pm = sc[u][0][0];
            #pragma unroll
            for (int ct = 0; ct < 4; ++ct)
                #pragma unroll
                for (int r = 0; r < 4; ++r)
                    pm = fmaxf(pm, sc[u][ct][r]);
            pm = fmaxf(pm, __shfl_xor(pm, 16));
            pm = fmaxf(pm, __shfl_xor(pm, 32));
            float mnew = fmaxf(m_run[u], pm);
            float al = exp2f(m_run[u] - mnew);
            m_run[u] = mnew;
            float ps = 0.0f;
            int prow = (u * 16 + c) * 64;
            #pragma unroll
            for (int ct = 0; ct < 4; ++ct) {
                bf16x4 pk;
                #pragma unroll
                for (int r = 0; r < 4; ++r) {
                    float p = exp2f(sc[u][ct][r] - mnew);
                    ps += p;
                    pk[r] = (short)(fbits(p) >> 16);
                }
                int phys = (ct * 2 + (quad >> 1)) ^ (c & 7);
                *(bf16x4*)(wp + prow + phys * 8 + (quad & 1) * 4) = pk;
            }
            ps += __shfl_xor(ps, 16);
            ps += __shfl_xor(ps, 32);
            l_run[u] = l_run[u] * al + ps;

            float alr[4];
            #pragma unroll
            for (int r = 0; r < 4; ++r)
                alr[r] = __shfl(al, (lane & 48) | (quad * 4 + r));
            #pragma unroll
            for (int ctd = 0; ctd < 4; ++ctd)
                #pragma unroll
                for (int r = 0; r < 4; ++r) acc[u][ctd][r] *= alr[r];
        }

        short8 pf[2][2];
        #pragma unroll
        for (int u = 0; u < 2; ++u) {
            int prow = (u * 16 + c) * 64, rw = c & 7;
            pf[u][0] = *(const short8*)(wp + prow + ((quad ^ rw) * 8));
            pf[u][1] = *(const short8*)(wp + prow + (((4 + quad) ^ rw) * 8));
        }
        #pragma unroll
        for (int ctd = 0; ctd < 4; ++ctd) {
            int vrow = ctd * 16 + c, vrw = vrow & 7;
            int vb = vrow * 64;
            short8 v0 = *(const short8*)(bVt + vb + ((quad ^ vrw) * 8));
            short8 v1 = *(const short8*)(bVt + vb + (((4 + quad) ^ vrw) * 8));
            #pragma unroll
            for (int u = 0; u < 2; ++u) {
                acc[u][ctd] = __builtin_amdgcn_mfma_f32_16x16x32_bf16(
                    pf[u][0], v0, acc[u][ctd], 0, 0, 0);
                acc[u][ctd] = __builtin_amdgcn_mfma_f32_16x16x32_bf16(
                    pf[u][1], v1, acc[u][ctd], 0, 0, 0);
            }
        }
    }
    #undef ISSUE_DMA

    #pragma unroll
    for (int u = 0; u < 2; ++u) {
        float rl[4];
        #pragma unroll
        for (int r = 0; r < 4; ++r)
            rl[r] = 1.0f / __shfl(l_run[u], (lane & 48) | (quad * 4 + r));
        #pragma unroll
        for (int ctd = 0; ctd < 4; ++ctd)
            #pragma unroll
            for (int r = 0; r < 4; ++r) {
                int s = q0 + w * 32 + u * 16 + quad * 4 + r;
                out[(size_t)(s * BATCH + b) * DIM + h * HD + ctd * 16 + c] =
                    acc[u][ctd][r] * rl[r];
            }
    }
}

// ---------------------------------------------------------------------------
extern "C" void kernel_launch(void* const* d_in, const int* in_sizes, int n_in,
                              void* d_out, int out_size, void* d_ws, size_t ws_size,
                              hipStream_t stream)
{
    const float* query = (const float*)d_in[0];
    const float* key_  = (const float*)d_in[1];
    const float* value = (const float*)d_in[2];
    const float* tmpl  = (const float*)d_in[3];
    const float* wq_cw = (const float*)d_in[4];
    const float* wq_cb = (const float*)d_in[5];
    const float* wq_b  = (const float*)d_in[6];
    const float* wk_cw = (const float*)d_in[7];
    const float* wk_cb = (const float*)d_in[8];
    const float* wk_b  = (const float*)d_in[9];
    const float* wv_cw = (const float*)d_in[10];
    const float* wv_cb = (const float*)d_in[11];
    const float* wv_b  = (const float*)d_in[12];

    char* ws = (char*)d_ws;
    u16* Wh = (u16*)(ws);
    u16* Wl = (u16*)(ws + 6291456);
    u16* Qh = (u16*)(ws + 12582912);
    u16* Ql = (u16*)(ws + 20971520);
    u16* Kh = (u16*)(ws + 29360128);
    u16* Kl = (u16*)(ws + 37748736);
    u16* Vb = (u16*)(ws + 46137344);
    u16* Vt = (u16*)(ws + 54525952);
    float* out = (float*)d_out;

    conv_weight_kernel<<<dim3(DIM / 256, DIM, 3), 256, 0, stream>>>(
        tmpl, wq_cw, wq_cb, wk_cw, wk_cb, wv_cw, wv_cb, Wh, Wl);

    qkv_mfma_gemm<<<dim3(DIM / 128, NROWS / 128, 3), 256, 0, stream>>>(
        query, key_, value, Wh, Wl, wq_b, wk_b, wv_b, Qh, Ql, Kh, Kl, Vb);

    vt_kernel<<<dim3(SLEN / 64, NHEAD, BATCH), 256, 0, stream>>>(Vb, Vt);

    attn_mfma_kernel<<<dim3(SLEN / 128, NHEAD, BATCH), 256, 0, stream>>>(
        Qh, Ql, Kh, Kl, Vt, out);
}